// Round 10
// baseline (322.242 us; speedup 1.0000x reference)
//
#include <hip/hip_runtime.h>
#include <cstddef>

#define NB 64
#define LL 512
#define HH 256
#define HD 128
#define NG 512
#define TI 16

typedef _Float16 half_t;
typedef _Float16 half8 __attribute__((ext_vector_type(8)));
typedef _Float16 half4 __attribute__((ext_vector_type(4)));
typedef float f32x4 __attribute__((ext_vector_type(4)));

#define MFMA16(a, b, c) __builtin_amdgcn_mfma_f32_16x16x32_f16((a), (b), (c), 0, 0, 0)

// LDS pitches (<=2-way bank aliasing, free on CDNA4)
#define FP 264   // sFeatb pitch (f16)
#define XP 518   // sXG pitch (f32); rows 0..18 used
#define HBP 136  // sHb pitch (f16)
#define EP 17    // sE inner pitch (f32)

// fast gates: v_rcp_f32 (~1 ulp) instead of full-precision divide.
__device__ __forceinline__ float sigm(float x)  { return __builtin_amdgcn_rcpf(1.0f + __expf(-x)); }
__device__ __forceinline__ float tanhf_(float x){ return 2.0f * __builtin_amdgcn_rcpf(1.0f + __expf(-2.0f * x)) - 1.0f; }

// 16-lane (DPP-row) sum on the VALU pipe: no DS ops.
template <int CTRL>
__device__ __forceinline__ float dppadd(float x) {
    int v = __builtin_amdgcn_update_dpp(0, __float_as_int(x), CTRL, 0xF, 0xF, true);
    return x + __int_as_float(v);
}
__device__ __forceinline__ float row16_sum(float x) {
    x = dppadd<0xB1>(x);    // quad_perm [1,0,3,2]
    x = dppadd<0x4E>(x);    // quad_perm [2,3,0,1]
    x = dppadd<0x141>(x);   // row_half_mirror
    x = dppadd<0x140>(x);   // row_mirror
    return x;
}

// Barrier with LDS visibility but NO vmcnt drain.
__device__ __forceinline__ void barrier_lgkm() {
    asm volatile("s_waitcnt lgkmcnt(0)" ::: "memory");
    __builtin_amdgcn_s_barrier();
    asm volatile("" ::: "memory");
}

// ---- prep: cast weights to f16, bsum = b_ih + b_hh ----
__global__ void prep_weights(const float* __restrict__ Wih, const float* __restrict__ Whh,
                             const float* __restrict__ bih, const float* __restrict__ bhh,
                             half_t* __restrict__ WihH, half_t* __restrict__ WhhH,
                             float* __restrict__ bsum)
{
    const int idx = blockIdx.x * 256 + threadIdx.x;
    if (idx < NG * HH) WihH[idx] = (half_t)Wih[idx];
    if (idx < NG * HD) WhhH[idx] = (half_t)Whh[idx];
    if (idx < NG)      bsum[idx] = bih[idx] + bhh[idx];
}

// R10: PERSISTENT BLOCKS. R9 showed avg residency ~0.7 blocks/CU against a
// 2-block cap -> the limiter is per-block fixed cost (launch/alloc, kernarg,
// lens/W_tri/bf2/Wih warmup), paid 2048x. Launch 512 blocks (2/CU, all
// resident at t=0); each loops 4 items: b = p&63 (lens loaded once),
// it = (p>>6)+8k ascending (first dead item terminates the loop; blocks with
// 16*(p>>6) >= lens_b exit after one compare). bf2/W_tri/b_tri are
// item-invariant and load once. Per-item LDS reuse is fenced by the existing
// barrier structure (sXG overwrite starts only after the sE-visible barrier).
__global__ __launch_bounds__(512, 4) void span_lstm_mfma(
    const float* __restrict__ feats, const half_t* __restrict__ WihH,
    const half_t* __restrict__ WhhH, const float* __restrict__ bsum,
    const float* __restrict__ W_tri, const float* __restrict__ b_tri,
    const int* __restrict__ lens, float* __restrict__ out)
{
    // 39,368 (sXG; sFeatb aliased inside) + 8,704 + 4,352 = 52,424 B
    __shared__ __align__(16) float  sXG[19 * XP];
    __shared__ __align__(16) half_t sHb[2][16 * HBP];
    __shared__ __align__(16) float  sE[4][16 * EP];   // [ts][s*EP + wv*2 + tag]

    half_t* sFeatb = (half_t*)sXG;   // dead after A-frag hoist (barrier-fenced)

    const int tid = threadIdx.x;
    const int p  = blockIdx.x;
    const int b  = p & 63;
    const int m  = p >> 6;           // first tile index; items: it = m + 8k
    const int lens_b = lens[b];
    if (m * TI >= lens_b) return;    // all 4 items dead

    const int lane = tid & 63, wv = tid >> 6;   // 8 waves
    const int lm = lane & 15;
    const int lq = lane >> 4;
    const int jw = wv * 16;
    const int gcol = jw + lm;

    // ---- item-invariant state: Whh B-frags (AGPR-backed), emit weights ----
    half8 bf2[4][4];
    #pragma unroll
    for (int ta = 0; ta < 4; ++ta)
        #pragma unroll
        for (int kf = 0; kf < 4; ++kf)
            bf2[ta][kf] = *(const half8*)(WhhH + (size_t)(ta * HD + gcol) * HD + kf * 32 + lq * 8);
    const float wt0 = W_tri[gcol];
    const float wt1 = W_tri[HD + gcol];
    const float bt0 = b_tri[0], bt1 = b_tri[1];
    float bs[4];
    #pragma unroll
    for (int ta = 0; ta < 4; ++ta) bs[ta] = bsum[ta * HD + gcol];

    const float* fb = feats + (size_t)b * LL * HH;
    float* obase = out + (size_t)b * LL * (LL * 2);

    for (int k = 0; k < 4; ++k) {
        const int i0 = (m + 8 * k) * TI;
        if (i0 >= lens_b) break;     // it ascending -> all later items dead too

        // ---- stage feats window (20 rows) as f16; rows >= lens_b never
        // selected -> stage zeros without loading ----
        for (int idx = tid; idx < 20 * 64; idx += 512) {
            const int pr = idx >> 6;
            const int k4 = (idx & 63) << 2;
            const int gp = i0 + pr;
            float4 v = make_float4(0.f, 0.f, 0.f, 0.f);
            if (gp < lens_b) v = *(const float4*)(fb + (size_t)gp * HH + k4);
            half4 hv = {(half_t)v.x, (half_t)v.y, (half_t)v.z, (half_t)v.w};
            *(half4*)(&sFeatb[pr * FP + k4]) = hv;
        }
        __syncthreads();

        // ---- hoist A-frags, fence before sXG overwrites aliased region ----
        half8 afr[2][8];
        #pragma unroll
        for (int mt = 0; mt < 2; ++mt)
            #pragma unroll
            for (int kf = 0; kf < 8; ++kf)
                afr[mt][kf] = *(const half8*)(&sFeatb[(16 * mt + lm) * FP + kf * 32 + lq * 8]);
        __syncthreads();

        // ---- phase 1: wave-private XG (4 ta x 16 cols); no barrier after ----
        #pragma unroll
        for (int ta = 0; ta < 4; ++ta) {
            const int gb = ta * HD + jw;
            f32x4 acc0 = {0.f, 0.f, 0.f, 0.f}, acc1 = {0.f, 0.f, 0.f, 0.f};
            #pragma unroll
            for (int kf = 0; kf < 8; ++kf) {
                const half8 bfr = *(const half8*)(WihH + (size_t)(gb + lm) * HH + kf * 32 + lq * 8);
                acc0 = MFMA16(afr[0][kf], bfr, acc0);
                acc1 = MFMA16(afr[1][kf], bfr, acc1);
            }
            #pragma unroll
            for (int r = 0; r < 4; ++r)
                sXG[(lq * 4 + r) * XP + gb + lm] = acc0[r] + bs[ta];
            if (lq == 0) {
                #pragma unroll
                for (int r = 0; r < 3; ++r)
                    sXG[(16 + r) * XP + gb + lm] = acc1[r] + bs[ta];
            }
        }

        float cc4[4] = {0.f, 0.f, 0.f, 0.f};
        float hhA[4][4];

        // ---- recurrence: minimal barrier-locked body ----
        #pragma unroll
        for (int t = 0; t < 4; ++t) {
            float accg[4][4];
            if (t > 0) {
                half8 ah[4];
                #pragma unroll
                for (int kf = 0; kf < 4; ++kf)
                    ah[kf] = *(const half8*)(&sHb[(t - 1) & 1][lm * HBP + kf * 32 + lq * 8]);
                #pragma unroll
                for (int ta = 0; ta < 4; ++ta) {
                    f32x4 a = {0.f, 0.f, 0.f, 0.f};
                    #pragma unroll
                    for (int kf = 0; kf < 4; ++kf)
                        a = MFMA16(ah[kf], bf2[ta][kf], a);
                    #pragma unroll
                    for (int r = 0; r < 4; ++r) accg[ta][r] = a[r];
                }
            } else {
                #pragma unroll
                for (int ta = 0; ta < 4; ++ta)
                    #pragma unroll
                    for (int r = 0; r < 4; ++r) accg[ta][r] = 0.f;
            }
            #pragma unroll
            for (int ta = 0; ta < 4; ++ta)
                #pragma unroll
                for (int r = 0; r < 4; ++r)
                    accg[ta][r] += sXG[(lq * 4 + r + t) * XP + ta * HD + gcol];

            #pragma unroll
            for (int r = 0; r < 4; ++r) {
                const float ig = sigm(accg[0][r]);
                const float fg = sigm(accg[1][r]);
                const float gg = tanhf_(accg[2][r]);
                const float og = sigm(accg[3][r]);
                cc4[r] = fg * cc4[r] + ig * gg;
                hhA[t][r] = og * tanhf_(cc4[r]);
            }

            if (t < 3) {
                #pragma unroll
                for (int r = 0; r < 4; ++r)
                    sHb[t & 1][(lq * 4 + r) * HBP + gcol] = (half_t)hhA[t][r];
                barrier_lgkm();
            }
        }

        // ---- emission: DPP row-sums, f32-exact ----
        #pragma unroll
        for (int ts = 0; ts < 4; ++ts)
            #pragma unroll
            for (int r = 0; r < 4; ++r) {
                float e0 = row16_sum(hhA[ts][r] * wt0);
                float e1 = row16_sum(hhA[ts][r] * wt1);
                if (lm == 0) {
                    float2 v = make_float2(e0, e1);
                    *(float2*)&sE[ts][(lq * 4 + r) * EP + wv * 2] = v;
                }
            }
        barrier_lgkm();   // sE visible; after this, sXG/sFeatb may be reused

        // ---- sparse value write (finalize merged): <=3 16B chunks/live row ----
        if (tid < 48) {
            const int es = tid & 15, mm = tid >> 4;
            const int i = i0 + es;
            const int rem = lens_b - i;
            if (rem > 0) {
                const int chi = ((i + 3 < LL) ? (i + 3) : (LL - 1)) >> 1;
                const int c = (i >> 1) + mm;
                if (c <= chi) {
                    const int j0 = 2 * c;
                    f32x4 v = {0.f, 0.f, 0.f, 0.f};
                    #pragma unroll
                    for (int half = 0; half < 2; ++half) {
                        const int w = j0 + half - i + 1;
                        if ((unsigned)(w - 1) < 4u && (j0 + half) < LL) {
                            const int ts = (rem < w ? rem : w) - 1;
                            float e0 = bt0, e1 = bt1;
                            #pragma unroll
                            for (int kk = 0; kk < 8; ++kk) {
                                e0 += sE[ts][es * EP + kk * 2 + 0];
                                e1 += sE[ts][es * EP + kk * 2 + 1];
                            }
                            if (half == 0) { v.x = e0; v.y = e1; }
                            else           { v.z = e0; v.w = e1; }
                        }
                    }
                    *(f32x4*)(obase + ((size_t)(i0 + es) * 512 + 2 * c) * 2) = v;
                }
            }
        }
        // next item's staging (writes sFeatb/sXG) is safe: every wave passed
        // the sE barrier, whose program order is after all sXG reads.
    }
}

extern "C" void kernel_launch(void* const* d_in, const int* in_sizes, int n_in,
                              void* d_out, int out_size, void* d_ws, size_t ws_size,
                              hipStream_t stream)
{
    const float* feats = (const float*)d_in[0];
    const float* W_ih  = (const float*)d_in[1];
    const float* W_hh  = (const float*)d_in[2];
    const float* b_ih  = (const float*)d_in[3];
    const float* b_hh  = (const float*)d_in[4];
    const float* W_tri = (const float*)d_in[5];
    const float* b_tri = (const float*)d_in[6];
    const int*   lens  = (const int*)d_in[7];
    float* out = (float*)d_out;

    // Bulk zeros via the driver blit (~6 TB/s; in-kernel streams cap at ~1.1).
    hipMemsetAsync(out, 0, (size_t)out_size * sizeof(float), stream);

    // ws layout: WihH (256 KB) | WhhH (128 KB) | bsum (2 KB)
    half_t* WihH = (half_t*)d_ws;
    half_t* WhhH = WihH + (size_t)NG * HH;
    float*  bsum = (float*)(WhhH + (size_t)NG * HD);

    prep_weights<<<(NG * HH + 255) / 256, 256, 0, stream>>>(W_ih, W_hh, b_ih, b_hh,
                                                            WihH, WhhH, bsum);
    // persistent grid: 512 blocks = 2/CU, 4 items each
    span_lstm_mfma<<<512, 512, 0, stream>>>(feats, WihH, WhhH, bsum,
                                            W_tri, b_tri, lens, out);
}

// Round 11
// 267.343 us; speedup vs baseline: 1.2054x; 1.2054x over previous
//
#include <hip/hip_runtime.h>
#include <cstddef>

#define NB 64
#define LL 512
#define HH 256
#define HD 128
#define NG 512
#define TI 16
#define NITEM 2048   // 32 tiles x 64 batches

typedef _Float16 half_t;
typedef _Float16 half8 __attribute__((ext_vector_type(8)));
typedef _Float16 half4 __attribute__((ext_vector_type(4)));
typedef float f32x4 __attribute__((ext_vector_type(4)));

#define MFMA16(a, b, c) __builtin_amdgcn_mfma_f32_16x16x32_f16((a), (b), (c), 0, 0, 0)

// LDS pitches (<=2-way bank aliasing, free on CDNA4)
#define FP 264   // sFeatb pitch (f16)
#define XP 518   // sXG pitch (f32); rows 0..18 used
#define HBP 136  // sHb pitch (f16)
#define EP 17    // sE inner pitch (f32)

// fast gates: v_rcp_f32 (~1 ulp) instead of full-precision divide.
__device__ __forceinline__ float sigm(float x)  { return __builtin_amdgcn_rcpf(1.0f + __expf(-x)); }
__device__ __forceinline__ float tanhf_(float x){ return 2.0f * __builtin_amdgcn_rcpf(1.0f + __expf(-2.0f * x)) - 1.0f; }

// 16-lane (DPP-row) sum on the VALU pipe: no DS ops.
template <int CTRL>
__device__ __forceinline__ float dppadd(float x) {
    int v = __builtin_amdgcn_update_dpp(0, __float_as_int(x), CTRL, 0xF, 0xF, true);
    return x + __int_as_float(v);
}
__device__ __forceinline__ float row16_sum(float x) {
    x = dppadd<0xB1>(x);    // quad_perm [1,0,3,2]
    x = dppadd<0x4E>(x);    // quad_perm [2,3,0,1]
    x = dppadd<0x141>(x);   // row_half_mirror
    x = dppadd<0x140>(x);   // row_mirror
    return x;
}

// Barrier with LDS visibility but NO vmcnt drain.
__device__ __forceinline__ void barrier_lgkm() {
    asm volatile("s_waitcnt lgkmcnt(0)" ::: "memory");
    __builtin_amdgcn_s_barrier();
    asm volatile("" ::: "memory");
}

// ---- prep: cast weights to f16, bsum = b_ih + b_hh, reset steal counter ----
__global__ void prep_weights(const float* __restrict__ Wih, const float* __restrict__ Whh,
                             const float* __restrict__ bih, const float* __restrict__ bhh,
                             half_t* __restrict__ WihH, half_t* __restrict__ WhhH,
                             float* __restrict__ bsum, int* __restrict__ ctr)
{
    const int idx = blockIdx.x * 256 + threadIdx.x;
    if (idx < NG * HH) WihH[idx] = (half_t)Wih[idx];
    if (idx < NG * HD) WhhH[idx] = (half_t)Whh[idx];
    if (idx < NG)      bsum[idx] = bih[idx] + bhh[idx];
    if (idx == 0)      *ctr = 0;
}

// R11: persistent blocks + WORK STEALING (R10 retried without its two bugs).
// R10's spill cause: hoisted bf2 (64r) live across the afr hoist (64r) -> >128
// peak -> 93/99 MB scratch traffic. Fix: sFeatb un-aliased and A-frags read
// inside the kf-loop (no afr array at all); phase-1 peak ~90 regs, t-loop
// identical to spill-free R9. R10's imbalance fix: global-counter stealing,
// tile-major item order (dead items cluster at the tail).
// 512 blocks = 2/CU (LDS 63 KB), all resident at t=0.
__global__ __launch_bounds__(512, 4) void span_lstm_mfma(
    const float* __restrict__ feats, const half_t* __restrict__ WihH,
    const half_t* __restrict__ WhhH, const float* __restrict__ bsum,
    const float* __restrict__ W_tri, const float* __restrict__ b_tri,
    const int* __restrict__ lens, int* __restrict__ ctr,
    float* __restrict__ out)
{
    // 10,560 + 39,368 + 8,704 + 4,352 + 16 = 63,000 B -> 2 blocks/CU
    __shared__ __align__(16) half_t sFeatb[20 * FP];
    __shared__ __align__(16) float  sXG[19 * XP];
    __shared__ __align__(16) half_t sHb[2][16 * HBP];
    __shared__ __align__(16) float  sE[4][16 * EP];   // [ts][s*EP + wv*2 + tag]
    __shared__ int sItem;

    const int tid = threadIdx.x;
    const int lane = tid & 63, wv = tid >> 6;   // 8 waves
    const int lm = lane & 15;
    const int lq = lane >> 4;
    const int jw = wv * 16;
    const int gcol = jw + lm;

    // ---- block-invariant state, loaded once per persistent block ----
    half8 bf2[4][4];
    #pragma unroll
    for (int ta = 0; ta < 4; ++ta)
        #pragma unroll
        for (int kf = 0; kf < 4; ++kf)
            bf2[ta][kf] = *(const half8*)(WhhH + (size_t)(ta * HD + gcol) * HD + kf * 32 + lq * 8);
    const float wt0 = W_tri[gcol];
    const float wt1 = W_tri[HD + gcol];
    const float bt0 = b_tri[0], bt1 = b_tri[1];
    float bs[4];
    #pragma unroll
    for (int ta = 0; ta < 4; ++ta) bs[ta] = bsum[ta * HD + gcol];

    for (;;) {
        if (tid == 0) sItem = atomicAdd(ctr, 1);
        __syncthreads();
        const int g = sItem;
        __syncthreads();            // sItem consumed before next write
        if (g >= NITEM) break;      // uniform exit

        const int it = g >> 6, b = g & 63;
        const int i0 = it * TI;
        const int lens_b = lens[b];
        if (i0 >= lens_b) continue; // dead item (tail of steal order)

        const float* fb = feats + (size_t)b * LL * HH;

        // ---- stage feats window (20 rows) as f16; rows >= lens_b never
        // selected -> stage zeros without loading ----
        for (int idx = tid; idx < 20 * 64; idx += 512) {
            const int pr = idx >> 6;
            const int k4 = (idx & 63) << 2;
            const int gp = i0 + pr;
            float4 v = make_float4(0.f, 0.f, 0.f, 0.f);
            if (gp < lens_b) v = *(const float4*)(fb + (size_t)gp * HH + k4);
            half4 hv = {(half_t)v.x, (half_t)v.y, (half_t)v.z, (half_t)v.w};
            *(half4*)(&sFeatb[pr * FP + k4]) = hv;
        }
        __syncthreads();

        // ---- phase 1: wave-private XG (4 ta x 16 cols); A-frags read from
        // LDS inside the kf loop (no 64-reg afr array -> no spill) ----
        #pragma unroll
        for (int ta = 0; ta < 4; ++ta) {
            const int gb = ta * HD + jw;
            f32x4 acc0 = {0.f, 0.f, 0.f, 0.f}, acc1 = {0.f, 0.f, 0.f, 0.f};
            #pragma unroll
            for (int kf = 0; kf < 8; ++kf) {
                const half8 a0 = *(const half8*)(&sFeatb[lm * FP        + kf * 32 + lq * 8]);
                const half8 a1 = *(const half8*)(&sFeatb[(16 + lm) * FP + kf * 32 + lq * 8]);
                const half8 bfr = *(const half8*)(WihH + (size_t)(gb + lm) * HH + kf * 32 + lq * 8);
                acc0 = MFMA16(a0, bfr, acc0);
                acc1 = MFMA16(a1, bfr, acc1);
            }
            #pragma unroll
            for (int r = 0; r < 4; ++r)
                sXG[(lq * 4 + r) * XP + gb + lm] = acc0[r] + bs[ta];
            if (lq == 0) {
                #pragma unroll
                for (int r = 0; r < 3; ++r)
                    sXG[(16 + r) * XP + gb + lm] = acc1[r] + bs[ta];
            }
        }

        float cc4[4] = {0.f, 0.f, 0.f, 0.f};
        float hhA[4][4];

        // ---- recurrence: minimal barrier-locked body ----
        #pragma unroll
        for (int t = 0; t < 4; ++t) {
            float accg[4][4];
            if (t > 0) {
                half8 ah[4];
                #pragma unroll
                for (int kf = 0; kf < 4; ++kf)
                    ah[kf] = *(const half8*)(&sHb[(t - 1) & 1][lm * HBP + kf * 32 + lq * 8]);
                #pragma unroll
                for (int ta = 0; ta < 4; ++ta) {
                    f32x4 a = {0.f, 0.f, 0.f, 0.f};
                    #pragma unroll
                    for (int kf = 0; kf < 4; ++kf)
                        a = MFMA16(ah[kf], bf2[ta][kf], a);
                    #pragma unroll
                    for (int r = 0; r < 4; ++r) accg[ta][r] = a[r];
                }
            } else {
                #pragma unroll
                for (int ta = 0; ta < 4; ++ta)
                    #pragma unroll
                    for (int r = 0; r < 4; ++r) accg[ta][r] = 0.f;
            }
            #pragma unroll
            for (int ta = 0; ta < 4; ++ta)
                #pragma unroll
                for (int r = 0; r < 4; ++r)
                    accg[ta][r] += sXG[(lq * 4 + r + t) * XP + ta * HD + gcol];

            #pragma unroll
            for (int r = 0; r < 4; ++r) {
                const float ig = sigm(accg[0][r]);
                const float fg = sigm(accg[1][r]);
                const float gg = tanhf_(accg[2][r]);
                const float og = sigm(accg[3][r]);
                cc4[r] = fg * cc4[r] + ig * gg;
                hhA[t][r] = og * tanhf_(cc4[r]);
            }

            if (t < 3) {
                #pragma unroll
                for (int r = 0; r < 4; ++r)
                    sHb[t & 1][(lq * 4 + r) * HBP + gcol] = (half_t)hhA[t][r];
                barrier_lgkm();
            }
        }

        // ---- emission: DPP row-sums, f32-exact ----
        #pragma unroll
        for (int ts = 0; ts < 4; ++ts)
            #pragma unroll
            for (int r = 0; r < 4; ++r) {
                float e0 = row16_sum(hhA[ts][r] * wt0);
                float e1 = row16_sum(hhA[ts][r] * wt1);
                if (lm == 0) {
                    float2 v = make_float2(e0, e1);
                    *(float2*)&sE[ts][(lq * 4 + r) * EP + wv * 2] = v;
                }
            }
        barrier_lgkm();   // sE visible

        // ---- sparse value write (finalize merged): <=3 16B chunks/live row ----
        if (tid < 48) {
            const int es = tid & 15, mm = tid >> 4;
            const int i = i0 + es;
            const int rem = lens_b - i;
            if (rem > 0) {
                const int chi = ((i + 3 < LL) ? (i + 3) : (LL - 1)) >> 1;
                const int c = (i >> 1) + mm;
                if (c <= chi) {
                    const int j0 = 2 * c;
                    f32x4 v = {0.f, 0.f, 0.f, 0.f};
                    #pragma unroll
                    for (int half = 0; half < 2; ++half) {
                        const int w = j0 + half - i + 1;
                        if ((unsigned)(w - 1) < 4u && (j0 + half) < LL) {
                            const int ts = (rem < w ? rem : w) - 1;
                            float e0 = bt0, e1 = bt1;
                            #pragma unroll
                            for (int kk = 0; kk < 8; ++kk) {
                                e0 += sE[ts][es * EP + kk * 2 + 0];
                                e1 += sE[ts][es * EP + kk * 2 + 1];
                            }
                            if (half == 0) { v.x = e0; v.y = e1; }
                            else           { v.z = e0; v.w = e1; }
                        }
                    }
                    float* ob = out + (size_t)b * LL * (LL * 2);
                    *(f32x4*)(ob + ((size_t)(i0 + es) * 512 + 2 * c) * 2) = v;
                }
            }
        }
        // next item's staging is fenced: every wave passed the sE barrier,
        // which is program-ordered after all sFeatb/sXG reads; the loop-top
        // __syncthreads covers the sItem rewrite.
    }
}

extern "C" void kernel_launch(void* const* d_in, const int* in_sizes, int n_in,
                              void* d_out, int out_size, void* d_ws, size_t ws_size,
                              hipStream_t stream)
{
    const float* feats = (const float*)d_in[0];
    const float* W_ih  = (const float*)d_in[1];
    const float* W_hh  = (const float*)d_in[2];
    const float* b_ih  = (const float*)d_in[3];
    const float* b_hh  = (const float*)d_in[4];
    const float* W_tri = (const float*)d_in[5];
    const float* b_tri = (const float*)d_in[6];
    const int*   lens  = (const int*)d_in[7];
    float* out = (float*)d_out;

    // Bulk zeros via the driver blit (~6 TB/s; in-kernel streams cap at ~1.1).
    hipMemsetAsync(out, 0, (size_t)out_size * sizeof(float), stream);

    // ws layout: WihH (256 KB) | WhhH (128 KB) | bsum (2 KB) | ctr (4 B)
    half_t* WihH = (half_t*)d_ws;
    half_t* WhhH = WihH + (size_t)NG * HH;
    float*  bsum = (float*)(WhhH + (size_t)NG * HD);
    int*    ctr  = (int*)(bsum + NG);

    prep_weights<<<(NG * HH + 255) / 256, 256, 0, stream>>>(W_ih, W_hh, b_ih, b_hh,
                                                            WihH, WhhH, bsum, ctr);
    // persistent grid: 512 blocks = 2/CU, work-stealing over 2048 items
    span_lstm_mfma<<<512, 512, 0, stream>>>(feats, WihH, WhhH, bsum,
                                            W_tri, b_tri, lens, ctr, out);
}

// Round 12
// 251.931 us; speedup vs baseline: 1.2791x; 1.0612x over previous
//
#include <hip/hip_runtime.h>
#include <cstddef>

#define NB 64
#define LL 512
#define HH 256
#define HD 128
#define NG 512
#define TI 16
#define NITEM 2048   // 32 tiles x 64 batches

typedef _Float16 half_t;
typedef _Float16 half8 __attribute__((ext_vector_type(8)));
typedef _Float16 half4 __attribute__((ext_vector_type(4)));
typedef float f32x4 __attribute__((ext_vector_type(4)));

#define MFMA16(a, b, c) __builtin_amdgcn_mfma_f32_16x16x32_f16((a), (b), (c), 0, 0, 0)

// LDS pitches (<=2-way bank aliasing, free on CDNA4)
#define FP 264   // sFeatb pitch (f16)
#define XP 518   // sXG pitch (f32); rows 0..18 used
#define HBP 136  // sHb pitch (f16)
#define EP 17    // sE inner pitch (f32)

// fast gates: v_rcp_f32 (~1 ulp) instead of full-precision divide.
__device__ __forceinline__ float sigm(float x)  { return __builtin_amdgcn_rcpf(1.0f + __expf(-x)); }
__device__ __forceinline__ float tanhf_(float x){ return 2.0f * __builtin_amdgcn_rcpf(1.0f + __expf(-2.0f * x)) - 1.0f; }

// 16-lane (DPP-row) sum on the VALU pipe: no DS ops.
template <int CTRL>
__device__ __forceinline__ float dppadd(float x) {
    int v = __builtin_amdgcn_update_dpp(0, __float_as_int(x), CTRL, 0xF, 0xF, true);
    return x + __int_as_float(v);
}
__device__ __forceinline__ float row16_sum(float x) {
    x = dppadd<0xB1>(x);    // quad_perm [1,0,3,2]
    x = dppadd<0x4E>(x);    // quad_perm [2,3,0,1]
    x = dppadd<0x141>(x);   // row_half_mirror
    x = dppadd<0x140>(x);   // row_mirror
    return x;
}

// Barrier with LDS visibility but NO vmcnt drain.
__device__ __forceinline__ void barrier_lgkm() {
    asm volatile("s_waitcnt lgkmcnt(0)" ::: "memory");
    __builtin_amdgcn_s_barrier();
    asm volatile("" ::: "memory");
}

// ---- prep: cast weights to f16, bsum = b_ih + b_hh, reset steal counter ----
__global__ void prep_weights(const float* __restrict__ Wih, const float* __restrict__ Whh,
                             const float* __restrict__ bih, const float* __restrict__ bhh,
                             half_t* __restrict__ WihH, half_t* __restrict__ WhhH,
                             float* __restrict__ bsum, int* __restrict__ ctr)
{
    const int idx = blockIdx.x * 256 + threadIdx.x;
    if (idx < NG * HH) WihH[idx] = (half_t)Wih[idx];
    if (idx < NG * HD) WhhH[idx] = (half_t)Whh[idx];
    if (idx < NG)      bsum[idx] = bih[idx] + bhh[idx];
    if (idx == 0)      *ctr = 0;
}

// R12: R11 (persistent 512 blocks + work stealing) with the spill removed.
// R11 lesson: bf2 (64 regs) held live ACROSS the item loop forces the
// allocator to spill/fill it around every item's staging+phase-1 region
// (~130 MB matched FETCH/WRITE scratch traffic). Fix = R9's proven placement:
// load bf2 per item, AFTER phase 1, when pressure is low. WhhH is 128 KB and
// L2-hot -- the per-item reload is noise next to a 128 KB/item spill.
__global__ __launch_bounds__(512, 4) void span_lstm_mfma(
    const float* __restrict__ feats, const half_t* __restrict__ WihH,
    const half_t* __restrict__ WhhH, const float* __restrict__ bsum,
    const float* __restrict__ W_tri, const float* __restrict__ b_tri,
    const int* __restrict__ lens, int* __restrict__ ctr,
    float* __restrict__ out)
{
    // 10,560 + 39,368 + 8,704 + 4,352 + 16 = 63,000 B -> 2 blocks/CU
    __shared__ __align__(16) half_t sFeatb[20 * FP];
    __shared__ __align__(16) float  sXG[19 * XP];
    __shared__ __align__(16) half_t sHb[2][16 * HBP];
    __shared__ __align__(16) float  sE[4][16 * EP];   // [ts][s*EP + wv*2 + tag]
    __shared__ int sItem;

    const int tid = threadIdx.x;
    const int lane = tid & 63, wv = tid >> 6;   // 8 waves
    const int lm = lane & 15;
    const int lq = lane >> 4;
    const int jw = wv * 16;
    const int gcol = jw + lm;

    // small block-invariant state only (6 VGPRs + SGPRs -- safe to hoist)
    const float wt0 = W_tri[gcol];
    const float wt1 = W_tri[HD + gcol];
    const float bt0 = b_tri[0], bt1 = b_tri[1];
    float bs[4];
    #pragma unroll
    for (int ta = 0; ta < 4; ++ta) bs[ta] = bsum[ta * HD + gcol];

    for (;;) {
        if (tid == 0) sItem = atomicAdd(ctr, 1);
        __syncthreads();
        const int g = sItem;
        __syncthreads();            // sItem consumed before next write
        if (g >= NITEM) break;      // uniform exit

        const int it = g >> 6, b = g & 63;
        const int i0 = it * TI;
        const int lens_b = lens[b];
        if (i0 >= lens_b) continue; // dead item (tail of steal order)

        const float* fb = feats + (size_t)b * LL * HH;

        // ---- stage feats window (20 rows) as f16; rows >= lens_b never
        // selected -> stage zeros without loading ----
        for (int idx = tid; idx < 20 * 64; idx += 512) {
            const int pr = idx >> 6;
            const int k4 = (idx & 63) << 2;
            const int gp = i0 + pr;
            float4 v = make_float4(0.f, 0.f, 0.f, 0.f);
            if (gp < lens_b) v = *(const float4*)(fb + (size_t)gp * HH + k4);
            half4 hv = {(half_t)v.x, (half_t)v.y, (half_t)v.z, (half_t)v.w};
            *(half4*)(&sFeatb[pr * FP + k4]) = hv;
        }
        __syncthreads();

        // ---- phase 1: wave-private XG (4 ta x 16 cols); A-frags read from
        // LDS inside the kf loop (no 64-reg afr array) ----
        #pragma unroll
        for (int ta = 0; ta < 4; ++ta) {
            const int gb = ta * HD + jw;
            f32x4 acc0 = {0.f, 0.f, 0.f, 0.f}, acc1 = {0.f, 0.f, 0.f, 0.f};
            #pragma unroll
            for (int kf = 0; kf < 8; ++kf) {
                const half8 a0 = *(const half8*)(&sFeatb[lm * FP        + kf * 32 + lq * 8]);
                const half8 a1 = *(const half8*)(&sFeatb[(16 + lm) * FP + kf * 32 + lq * 8]);
                const half8 bfr = *(const half8*)(WihH + (size_t)(gb + lm) * HH + kf * 32 + lq * 8);
                acc0 = MFMA16(a0, bfr, acc0);
                acc1 = MFMA16(a1, bfr, acc1);
            }
            #pragma unroll
            for (int r = 0; r < 4; ++r)
                sXG[(lq * 4 + r) * XP + gb + lm] = acc0[r] + bs[ta];
            if (lq == 0) {
                #pragma unroll
                for (int r = 0; r < 3; ++r)
                    sXG[(16 + r) * XP + gb + lm] = acc1[r] + bs[ta];
            }
        }

        // ---- Whh B-frags loaded HERE (per item, low-pressure point):
        // lifetime = t-loop + emission only -> no loop-carried 64-reg set ----
        half8 bf2[4][4];
        #pragma unroll
        for (int ta = 0; ta < 4; ++ta)
            #pragma unroll
            for (int kf = 0; kf < 4; ++kf)
                bf2[ta][kf] = *(const half8*)(WhhH + (size_t)(ta * HD + gcol) * HD + kf * 32 + lq * 8);

        float cc4[4] = {0.f, 0.f, 0.f, 0.f};
        float hhA[4][4];

        // ---- recurrence: minimal barrier-locked body ----
        #pragma unroll
        for (int t = 0; t < 4; ++t) {
            float accg[4][4];
            if (t > 0) {
                half8 ah[4];
                #pragma unroll
                for (int kf = 0; kf < 4; ++kf)
                    ah[kf] = *(const half8*)(&sHb[(t - 1) & 1][lm * HBP + kf * 32 + lq * 8]);
                #pragma unroll
                for (int ta = 0; ta < 4; ++ta) {
                    f32x4 a = {0.f, 0.f, 0.f, 0.f};
                    #pragma unroll
                    for (int kf = 0; kf < 4; ++kf)
                        a = MFMA16(ah[kf], bf2[ta][kf], a);
                    #pragma unroll
                    for (int r = 0; r < 4; ++r) accg[ta][r] = a[r];
                }
            } else {
                #pragma unroll
                for (int ta = 0; ta < 4; ++ta)
                    #pragma unroll
                    for (int r = 0; r < 4; ++r) accg[ta][r] = 0.f;
            }
            #pragma unroll
            for (int ta = 0; ta < 4; ++ta)
                #pragma unroll
                for (int r = 0; r < 4; ++r)
                    accg[ta][r] += sXG[(lq * 4 + r + t) * XP + ta * HD + gcol];

            #pragma unroll
            for (int r = 0; r < 4; ++r) {
                const float ig = sigm(accg[0][r]);
                const float fg = sigm(accg[1][r]);
                const float gg = tanhf_(accg[2][r]);
                const float og = sigm(accg[3][r]);
                cc4[r] = fg * cc4[r] + ig * gg;
                hhA[t][r] = og * tanhf_(cc4[r]);
            }

            if (t < 3) {
                #pragma unroll
                for (int r = 0; r < 4; ++r)
                    sHb[t & 1][(lq * 4 + r) * HBP + gcol] = (half_t)hhA[t][r];
                barrier_lgkm();
            }
        }

        // ---- emission: DPP row-sums, f32-exact ----
        #pragma unroll
        for (int ts = 0; ts < 4; ++ts)
            #pragma unroll
            for (int r = 0; r < 4; ++r) {
                float e0 = row16_sum(hhA[ts][r] * wt0);
                float e1 = row16_sum(hhA[ts][r] * wt1);
                if (lm == 0) {
                    float2 v = make_float2(e0, e1);
                    *(float2*)&sE[ts][(lq * 4 + r) * EP + wv * 2] = v;
                }
            }
        barrier_lgkm();   // sE visible

        // ---- sparse value write (finalize merged): <=3 16B chunks/live row ----
        if (tid < 48) {
            const int es = tid & 15, mm = tid >> 4;
            const int i = i0 + es;
            const int rem = lens_b - i;
            if (rem > 0) {
                const int chi = ((i + 3 < LL) ? (i + 3) : (LL - 1)) >> 1;
                const int c = (i >> 1) + mm;
                if (c <= chi) {
                    const int j0 = 2 * c;
                    f32x4 v = {0.f, 0.f, 0.f, 0.f};
                    #pragma unroll
                    for (int half = 0; half < 2; ++half) {
                        const int w = j0 + half - i + 1;
                        if ((unsigned)(w - 1) < 4u && (j0 + half) < LL) {
                            const int ts = (rem < w ? rem : w) - 1;
                            float e0 = bt0, e1 = bt1;
                            #pragma unroll
                            for (int kk = 0; kk < 8; ++kk) {
                                e0 += sE[ts][es * EP + kk * 2 + 0];
                                e1 += sE[ts][es * EP + kk * 2 + 1];
                            }
                            if (half == 0) { v.x = e0; v.y = e1; }
                            else           { v.z = e0; v.w = e1; }
                        }
                    }
                    float* ob = out + (size_t)b * LL * (LL * 2);
                    *(f32x4*)(ob + ((size_t)(i0 + es) * 512 + 2 * c) * 2) = v;
                }
            }
        }
        // next item's staging is fenced: every wave passed the sE barrier,
        // which is program-ordered after all sFeatb/sXG reads; the loop-top
        // __syncthreads covers the sItem rewrite.
    }
}

extern "C" void kernel_launch(void* const* d_in, const int* in_sizes, int n_in,
                              void* d_out, int out_size, void* d_ws, size_t ws_size,
                              hipStream_t stream)
{
    const float* feats = (const float*)d_in[0];
    const float* W_ih  = (const float*)d_in[1];
    const float* W_hh  = (const float*)d_in[2];
    const float* b_ih  = (const float*)d_in[3];
    const float* b_hh  = (const float*)d_in[4];
    const float* W_tri = (const float*)d_in[5];
    const float* b_tri = (const float*)d_in[6];
    const int*   lens  = (const int*)d_in[7];
    float* out = (float*)d_out;

    // Bulk zeros via the driver blit (~6 TB/s; in-kernel streams cap at ~1.1).
    hipMemsetAsync(out, 0, (size_t)out_size * sizeof(float), stream);

    // ws layout: WihH (256 KB) | WhhH (128 KB) | bsum (2 KB) | ctr (4 B)
    half_t* WihH = (half_t*)d_ws;
    half_t* WhhH = WihH + (size_t)NG * HH;
    float*  bsum = (float*)(WhhH + (size_t)NG * HD);
    int*    ctr  = (int*)(bsum + NG);

    prep_weights<<<(NG * HH + 255) / 256, 256, 0, stream>>>(W_ih, W_hh, b_ih, b_hh,
                                                            WihH, WhhH, bsum, ctr);
    // persistent grid: 512 blocks = 2/CU, work-stealing over 2048 items
    span_lstm_mfma<<<512, 512, 0, stream>>>(feats, WihH, WhhH, bsum,
                                            W_tri, b_tri, lens, ctr, out);
}